// Round 5
// baseline (133.340 us; speedup 1.0000x reference)
//
#include <hip/hip_runtime.h>
#include <math.h>

#define BATCH 65536
#define DT_C 0.0166667f
#define NN_RATIO_C 0.3f

typedef __bf16 bf16x8 __attribute__((ext_vector_type(8)));
typedef unsigned short us8 __attribute__((ext_vector_type(8)));
typedef float f32x4 __attribute__((ext_vector_type(4)));

union FragU { us8 u; bf16x8 b; unsigned d[4]; };

__device__ __forceinline__ unsigned short f2bf(float f) {
    union { __bf16 h; unsigned short u; } v;
    v.h = (__bf16)f;                        // hardware RTNE cvt
    return v.u;
}
__device__ __forceinline__ unsigned pk2(float lo, float hi) {
    return (unsigned)f2bf(lo) | ((unsigned)f2bf(hi) << 16);
}
__device__ __forceinline__ float up_lo(unsigned u) { return __uint_as_float(u << 16); }
__device__ __forceinline__ float up_hi(unsigned u) { return __uint_as_float(u & 0xFFFF0000u); }
// e must be compile-time (fully unrolled callers)
__device__ __forceinline__ float upk(const unsigned* p, int e) {
    return (e & 1) ? up_hi(p[e >> 1]) : up_lo(p[e >> 1]);
}
__device__ __forceinline__ float lrelu(float x) { return fmaxf(x, 0.01f * x); }

// Block = 512 threads = 8 waves; wave w == muscle w; 64 rows/block, 1024 blocks.
// __launch_bounds__(512,6): VGPR<=85 -> 3 blocks/CU = 6 waves/SIMD (was 4).
// Chain cuts vs R4:
//  - layer 1 computed scalar, directly in B-frag layout (lane(q,b): k=q*8+j of
//    row b) -> first LDS transpose round trip eliminated.
//  - layer-4 quad-reduction + tanh moved out of the loop: lanes write per-quad
//    dot partials + (kterm,bflin,coeff) to LDS; same-wave in-order DS means the
//    post-loop phase needs NO barrier. Only one __syncthreads in the kernel.
// MFMA orientation (verified R3/R4): D[o][b] = sum_i W[o][i]*X[b][i];
//   A-frag W[o=t*16+n16][i=quad*8+j], B-frag X[b=n16][i=quad*8+j],
//   D lane = col b=n16, rows o=quad*4+reg.
__global__ __launch_bounds__(512, 6) void joint_kernel(
    const float* __restrict__ SS, const float* __restrict__ Alphas,
    const float* __restrict__ K0s, const float* __restrict__ K1s,
    const float* __restrict__ L0s, const float* __restrict__ L1s,
    const float* __restrict__ Ms, const float* __restrict__ Ivec,
    const float* __restrict__ Bv, const float* __restrict__ Kv,
    const float* __restrict__ W1, const float* __restrict__ b1,
    const float* __restrict__ W2, const float* __restrict__ b2,
    const float* __restrict__ W3, const float* __restrict__ b3,
    const float* __restrict__ W4, const float* __restrict__ b4,
    float* __restrict__ out)
{
    __shared__ unsigned short Xbuf[8][16 * 40];  // per-wave transpose tile
    __shared__ float comb[8][8][64];             // [m][slot][row]: 0-3 dot partials, 4 kterm, 5 bflin, 6 coeff
    __shared__ float red2k[8][64];
    __shared__ float red2bf[8][64];

    const int tid  = threadIdx.x;
    const int lane = tid & 63;
    const int w    = tid >> 6;
    const int m    = __builtin_amdgcn_readfirstlane(w);
    const int n16  = lane & 15;
    const int quad = lane >> 4;

    // wave-uniform scalars -> SGPRs
    const float ms = Ms[m];
    const float k0 = K0s[m], k1 = K1s[m], l0 = L0s[m], l1 = L1s[m];
    const float b4m = b4[m];

    // ---- packed weights (bf16 pairs) to keep VGPR under the 6-wave cap ----
    unsigned w1p[12], b1p[4], b2p[4], b3p[4], w4p[4];
    FragU w2f[2], w3f[2];
    {
        const float* p1 = W1 + m * 96 + quad * 24;   // W1[m][o=q*8+j][c], 24 floats
        #pragma unroll
        for (int k = 0; k < 12; ++k) w1p[k] = pk2(p1[2 * k], p1[2 * k + 1]);
        const float* pb1 = b1 + m * 32 + quad * 8;
        #pragma unroll
        for (int k = 0; k < 4; ++k) b1p[k] = pk2(pb1[2 * k], pb1[2 * k + 1]);

        #pragma unroll
        for (int t = 0; t < 2; ++t) {
            const int o = t * 16 + n16;
            const float* p2 = W2 + m * 1024 + o * 32 + quad * 8;
            const float* p3 = W3 + m * 1024 + o * 32 + quad * 8;
            f32x4 a2 = *(const f32x4*)p2, c2 = *(const f32x4*)(p2 + 4);
            f32x4 a3 = *(const f32x4*)p3, c3 = *(const f32x4*)(p3 + 4);
            w2f[t].d[0] = pk2(a2[0], a2[1]); w2f[t].d[1] = pk2(a2[2], a2[3]);
            w2f[t].d[2] = pk2(c2[0], c2[1]); w2f[t].d[3] = pk2(c2[2], c2[3]);
            w3f[t].d[0] = pk2(a3[0], a3[1]); w3f[t].d[1] = pk2(a3[2], a3[3]);
            w3f[t].d[2] = pk2(c3[0], c3[1]); w3f[t].d[3] = pk2(c3[2], c3[3]);
        }
        const float* pb2 = b2 + m * 32 + quad * 4;
        b2p[0] = pk2(pb2[0],  pb2[1]);  b2p[1] = pk2(pb2[2],  pb2[3]);
        b2p[2] = pk2(pb2[16], pb2[17]); b2p[3] = pk2(pb2[18], pb2[19]);
        const float* pb3 = b3 + m * 32 + quad * 4;
        b3p[0] = pk2(pb3[0],  pb3[1]);  b3p[1] = pk2(pb3[2],  pb3[3]);
        b3p[2] = pk2(pb3[16], pb3[17]); b3p[3] = pk2(pb3[18], pb3[19]);
        const float* pw4 = W4 + m * 32 + quad * 4;
        w4p[0] = pk2(pw4[0],  pw4[1]);  w4p[1] = pk2(pw4[2],  pw4[3]);
        w4p[2] = pk2(pw4[16], pw4[17]); w4p[3] = pk2(pw4[18], pw4[19]);
    }

    unsigned short* const X = &Xbuf[w][0];
    const int rowbase = blockIdx.x * 64;

    #pragma unroll 1
    for (int s = 0; s < 4; ++s) {
        const int bb = rowbase + s * 16 + n16;
        const float2 ssv = *(const float2*)&SS[2 * bb];
        float a = Alphas[8 * bb + m];
        a = fminf(fmaxf(a, 0.0f), 1.0f);
        const float l  = ssv.x * ms;
        const float dl = ssv.y * ms;

        // ---- layer 1, scalar, directly in B-frag layout (k = quad*8+j) ----
        float hv[8];
        #pragma unroll
        for (int j = 0; j < 8; ++j) {
            float acc = upk(b1p, j)
                      + upk(w1p, 3 * j + 0) * l
                      + upk(w1p, 3 * j + 1) * dl
                      + upk(w1p, 3 * j + 2) * a;
            hv[j] = lrelu(acc);
        }
        FragU h1;
        h1.d[0] = pk2(hv[0], hv[1]); h1.d[1] = pk2(hv[2], hv[3]);
        h1.d[2] = pk2(hv[4], hv[5]); h1.d[3] = pk2(hv[6], hv[7]);

        // ---- layer 2 (MFMA) ----
        f32x4 c0, c1;
        c0[0] = up_lo(b2p[0]); c0[1] = up_hi(b2p[0]); c0[2] = up_lo(b2p[1]); c0[3] = up_hi(b2p[1]);
        c1[0] = up_lo(b2p[2]); c1[1] = up_hi(b2p[2]); c1[2] = up_lo(b2p[3]); c1[3] = up_hi(b2p[3]);
        f32x4 acc0 = __builtin_amdgcn_mfma_f32_16x16x32_bf16(w2f[0].b, h1.b, c0, 0, 0, 0);
        f32x4 acc1 = __builtin_amdgcn_mfma_f32_16x16x32_bf16(w2f[1].b, h1.b, c1, 0, 0, 0);

        // ---- transpose via LDS (the one remaining round trip) ----
        uint2 st0, st1;
        st0.x = pk2(lrelu(acc0[0]), lrelu(acc0[1]));
        st0.y = pk2(lrelu(acc0[2]), lrelu(acc0[3]));
        st1.x = pk2(lrelu(acc1[0]), lrelu(acc1[1]));
        st1.y = pk2(lrelu(acc1[2]), lrelu(acc1[3]));
        *(uint2*)&X[n16 * 40 + quad * 4]      = st0;   // rows o=quad*4+r
        *(uint2*)&X[n16 * 40 + 16 + quad * 4] = st1;   // rows o=16+quad*4+r

        FragU hf;
        hf.u = *(const us8*)&X[n16 * 40 + quad * 8];   // row n16, k=quad*8+j

        // ---- layer 3 (MFMA) ----
        c0[0] = up_lo(b3p[0]); c0[1] = up_hi(b3p[0]); c0[2] = up_lo(b3p[1]); c0[3] = up_hi(b3p[1]);
        c1[0] = up_lo(b3p[2]); c1[1] = up_hi(b3p[2]); c1[2] = up_lo(b3p[3]); c1[3] = up_hi(b3p[3]);
        acc0 = __builtin_amdgcn_mfma_f32_16x16x32_bf16(w3f[0].b, hf.b, c0, 0, 0, 0);
        acc1 = __builtin_amdgcn_mfma_f32_16x16x32_bf16(w3f[1].b, hf.b, c1, 0, 0, 0);

        // ---- layer-4 per-quad dot partial (no shfl, no exp in the loop) ----
        float d = lrelu(acc0[0]) * up_lo(w4p[0]) + lrelu(acc0[1]) * up_hi(w4p[0])
                + lrelu(acc0[2]) * up_lo(w4p[1]) + lrelu(acc0[3]) * up_hi(w4p[1])
                + lrelu(acc1[0]) * up_lo(w4p[2]) + lrelu(acc1[1]) * up_hi(w4p[2])
                + lrelu(acc1[2]) * up_lo(w4p[3]) + lrelu(acc1[3]) * up_hi(w4p[3]);

        const int row = s * 16 + n16;
        comb[w][quad][row] = d;
        // quads 1..3 carry the three BF components (all quads hold a,l)
        const float kk = k0 + k1 * a;
        float auxv = kk * ms * ms;                                   // quad 1: kterm
        if (quad == 2) auxv = kk * (l0 + l1 * a - fabsf(l)) * ms;    // bflin
        if (quad == 3) auxv = k1 * l1 * a * a * ms;                  // coeff
        if (quad >= 1) comb[w][3 + quad][row] = auxv;
    }

    // ---- phase 1: per-(m,row) tanh + quad reduction. Same-wave in-order DS:
    // wave w reads only comb[w][...] it wrote itself -> no barrier needed.
    {
        const int r = lane;
        float dot = comb[w][0][r] + comb[w][1][r] + comb[w][2][r] + comb[w][3][r];
        const float kterm = comb[w][4][r];
        const float bflin = comb[w][5][r];
        const float coeff = comb[w][6][r];
        const float e2x = __expf(2.0f * (dot + b4m));
        const float nn = (1.0f - 2.0f / (e2x + 1.0f)) * NN_RATIO_C;
        red2k[w][r]  = kterm;
        red2bf[w][r] = bflin + coeff * nn;
    }

    __syncthreads();

    if (tid < 64) {
        float Ksum = 0.0f, BFsum = 0.0f;
        #pragma unroll
        for (int mm = 0; mm < 8; ++mm) {
            Ksum  += red2k[mm][tid];
            BFsum += red2bf[mm][tid];
        }

        const int b = rowbase + tid;
        const float2 ssv = *(const float2*)&SS[2 * b];
        const float s0 = ssv.x, s1 = ssv.y;
        const float I  = Ivec[0];
        const float bv = Bv[0];
        const float kv = Kv[0];
        const float inv_I = 1.0f / I;

        const float A10 = -(Ksum + kv) * inv_I;
        const float D   = 2.0f * sqrtf(Ksum * I);
        const float A11 = -(D + bv) * inv_I;
        const float B10 = BFsum * inv_I;

        // Reduced 3x3 expm (verified R1-R4)
        const float m01 = DT_C;
        const float m10 = A10 * DT_C, m11 = A11 * DT_C, m12 = B10 * DT_C;

        float p00 = 0.0f, p01 = m01, p02 = 0.0f;
        float p10 = m10,  p11 = m11, p12 = m12;
        float t00 = p00, t01 = p01, t02 = p02;
        float t10 = p10, t11 = p11, t12 = p12;
        #pragma unroll
        for (int k = 2; k <= 16; ++k) {
            float inv = 1.0f / (float)k;
            float q00 = (p01 * m10) * inv;
            float q01 = (p00 * m01 + p01 * m11) * inv;
            float q02 = (p01 * m12) * inv;
            float q10 = (p11 * m10) * inv;
            float q11 = (p10 * m01 + p11 * m11) * inv;
            float q12 = (p11 * m12) * inv;
            p00 = q00; p01 = q01; p02 = q02;
            p10 = q10; p11 = q11; p12 = q12;
            t00 += p00; t01 += p01; t02 += p02;
            t10 += p10; t11 += p11; t12 += p12;
        }
        const float E00 = 1.0f + t00, E01 = t01, c0 = t02;
        const float E10 = t10,        E11 = 1.0f + t11, c1 = t12;

        const float o0 = E00 * s0 + E01 * s1 + c0;
        const float o1 = E10 * s0 + E11 * s1 + c1;

        out[b] = o0;                               // output 0: SSout[:,0:1]
        float2 o12; o12.x = o0; o12.y = o1;        // output 1: SSout[:,:,0]
        *(float2*)&out[BATCH + 2 * b] = o12;
    }
}

extern "C" void kernel_launch(void* const* d_in, const int* in_sizes, int n_in,
                              void* d_out, int out_size, void* d_ws, size_t ws_size,
                              hipStream_t stream) {
    const float* SS     = (const float*)d_in[0];
    const float* Alphas = (const float*)d_in[1];
    const float* K0s    = (const float*)d_in[2];
    const float* K1s    = (const float*)d_in[3];
    const float* L0s    = (const float*)d_in[4];
    const float* L1s    = (const float*)d_in[5];
    const float* Ms     = (const float*)d_in[6];
    const float* I      = (const float*)d_in[7];
    const float* Bv     = (const float*)d_in[8];
    const float* Kv     = (const float*)d_in[9];
    const float* W1     = (const float*)d_in[10];
    const float* b1     = (const float*)d_in[11];
    const float* W2     = (const float*)d_in[12];
    const float* b2     = (const float*)d_in[13];
    const float* W3     = (const float*)d_in[14];
    const float* b3     = (const float*)d_in[15];
    const float* W4     = (const float*)d_in[16];
    const float* b4     = (const float*)d_in[17];
    float* out = (float*)d_out;

    joint_kernel<<<BATCH / 64, 512, 0, stream>>>(
        SS, Alphas, K0s, K1s, L0s, L1s, Ms, I, Bv, Kv,
        W1, b1, W2, b2, W3, b3, W4, b4, out);
}

// Round 6
// 104.332 us; speedup vs baseline: 1.2780x; 1.2780x over previous
//
#include <hip/hip_runtime.h>
#include <math.h>

#define BATCH 65536
#define DT_C 0.0166667f
#define NN_RATIO_C 0.3f

typedef __bf16 bf16x8 __attribute__((ext_vector_type(8)));
typedef unsigned short us8 __attribute__((ext_vector_type(8)));
typedef float f32x4 __attribute__((ext_vector_type(4)));

union FragU { us8 u; bf16x8 b; unsigned d[4]; };

__device__ __forceinline__ unsigned short f2bf(float f) {
    union { __bf16 h; unsigned short u; } v;
    v.h = (__bf16)f;                        // hardware RTNE cvt
    return v.u;
}
__device__ __forceinline__ unsigned pk2(float lo, float hi) {
    return (unsigned)f2bf(lo) | ((unsigned)f2bf(hi) << 16);
}
__device__ __forceinline__ float up_lo(unsigned u) { return __uint_as_float(u << 16); }
__device__ __forceinline__ float up_hi(unsigned u) { return __uint_as_float(u & 0xFFFF0000u); }
__device__ __forceinline__ float upk(const unsigned* p, int e) {   // e compile-time
    return (e & 1) ? up_hi(p[e >> 1]) : up_lo(p[e >> 1]);
}
__device__ __forceinline__ float lrelu(float x) { return fmaxf(x, 0.01f * x); }

// Block = 512 threads = 8 waves; wave w == muscle w; 128 rows/block, 512 blocks.
// __launch_bounds__(512,4): 128-VGPR cap (R4's natural occupancy, spill-free).
// R5 post-mortem: (512,6)'s 85-VGPR cap caused scratch spills (WRITE_SIZE
// 768KB->47MB) and comb's 64-float slot stride caused 4-way LDS conflicts
// (491K). Fixes: relaxed cap; comb slot stride padded to 136 floats
// (136%32==8 -> quad windows offset by 8 banks -> max 2-way aliasing = free).
// Kept from R5 (verified, absmax 1.95e-3): scalar layer-1 directly in B-frag
// layout; deferred tanh/quad-reduction (single __syncthreads).
// Re-added from R4: dual 16-row streams per iteration for latency hiding.
// MFMA orientation (verified R3-R5): D[o][b] = sum_i W[o][i]*X[b][i];
//   A-frag W[o=t*16+n16][i=quad*8+j], B-frag X[b=n16][i=quad*8+j],
//   D lane = col b=n16, rows o=quad*4+reg.
__global__ __launch_bounds__(512, 4) void joint_kernel(
    const float* __restrict__ SS, const float* __restrict__ Alphas,
    const float* __restrict__ K0s, const float* __restrict__ K1s,
    const float* __restrict__ L0s, const float* __restrict__ L1s,
    const float* __restrict__ Ms, const float* __restrict__ Ivec,
    const float* __restrict__ Bv, const float* __restrict__ Kv,
    const float* __restrict__ W1, const float* __restrict__ b1,
    const float* __restrict__ W2, const float* __restrict__ b2,
    const float* __restrict__ W3, const float* __restrict__ b3,
    const float* __restrict__ W4, const float* __restrict__ b4,
    float* __restrict__ out)
{
    __shared__ unsigned short Xbuf[16][640];  // [wave*2+stream][16 rows * 40]
    // slots: 0-3 dot partials (per quad), 4 kterm, 5 bflin, 6 coeff.
    // slot stride 136 floats: 136%32==8 -> <=2-way bank aliasing (free).
    __shared__ float comb[8][7][136];
    __shared__ float red2bf[8][128];

    const int tid  = threadIdx.x;
    const int lane = tid & 63;
    const int w    = tid >> 6;
    const int m    = __builtin_amdgcn_readfirstlane(w);
    const int n16  = lane & 15;
    const int quad = lane >> 4;

    // wave-uniform scalars -> SGPRs
    const float ms = Ms[m];
    const float k0 = K0s[m], k1 = K1s[m], l0 = L0s[m], l1 = L1s[m];
    const float b4m = b4[m];

    // ---- packed weights (bf16 pairs): ~44 persistent VGPRs ----
    unsigned w1p[12], b1p[4], b2p[4], b3p[4], w4p[4];
    FragU w2f[2], w3f[2];
    {
        const float* p1 = W1 + m * 96 + quad * 24;   // W1[m][o=quad*8+j][c]
        #pragma unroll
        for (int k = 0; k < 12; ++k) w1p[k] = pk2(p1[2 * k], p1[2 * k + 1]);
        const float* pb1 = b1 + m * 32 + quad * 8;
        #pragma unroll
        for (int k = 0; k < 4; ++k) b1p[k] = pk2(pb1[2 * k], pb1[2 * k + 1]);

        #pragma unroll
        for (int t = 0; t < 2; ++t) {
            const int o = t * 16 + n16;
            const float* p2 = W2 + m * 1024 + o * 32 + quad * 8;
            const float* p3 = W3 + m * 1024 + o * 32 + quad * 8;
            f32x4 a2 = *(const f32x4*)p2, c2 = *(const f32x4*)(p2 + 4);
            f32x4 a3 = *(const f32x4*)p3, c3 = *(const f32x4*)(p3 + 4);
            w2f[t].d[0] = pk2(a2[0], a2[1]); w2f[t].d[1] = pk2(a2[2], a2[3]);
            w2f[t].d[2] = pk2(c2[0], c2[1]); w2f[t].d[3] = pk2(c2[2], c2[3]);
            w3f[t].d[0] = pk2(a3[0], a3[1]); w3f[t].d[1] = pk2(a3[2], a3[3]);
            w3f[t].d[2] = pk2(c3[0], c3[1]); w3f[t].d[3] = pk2(c3[2], c3[3]);
        }
        const float* pb2 = b2 + m * 32 + quad * 4;
        b2p[0] = pk2(pb2[0],  pb2[1]);  b2p[1] = pk2(pb2[2],  pb2[3]);
        b2p[2] = pk2(pb2[16], pb2[17]); b2p[3] = pk2(pb2[18], pb2[19]);
        const float* pb3 = b3 + m * 32 + quad * 4;
        b3p[0] = pk2(pb3[0],  pb3[1]);  b3p[1] = pk2(pb3[2],  pb3[3]);
        b3p[2] = pk2(pb3[16], pb3[17]); b3p[3] = pk2(pb3[18], pb3[19]);
        const float* pw4 = W4 + m * 32 + quad * 4;
        w4p[0] = pk2(pw4[0],  pw4[1]);  w4p[1] = pk2(pw4[2],  pw4[3]);
        w4p[2] = pk2(pw4[16], pw4[17]); w4p[3] = pk2(pw4[18], pw4[19]);
    }

    unsigned short* const X0 = &Xbuf[2 * w][0];
    unsigned short* const X1 = &Xbuf[2 * w + 1][0];
    const int rowbase = blockIdx.x * 128;

    #pragma unroll 1
    for (int s = 0; s < 8; s += 2) {
        float lv[2], av[2];
        FragU h1[2];
        #pragma unroll
        for (int p = 0; p < 2; ++p) {
            const int bb = rowbase + (s + p) * 16 + n16;
            const float2 ssv = *(const float2*)&SS[2 * bb];
            float a = Alphas[8 * bb + m];
            a = fminf(fmaxf(a, 0.0f), 1.0f);
            av[p] = a;
            const float l  = ssv.x * ms;
            const float dl = ssv.y * ms;
            lv[p] = l;

            // layer 1, scalar, directly in B-frag layout (k = quad*8+j)
            float hv[8];
            #pragma unroll
            for (int j = 0; j < 8; ++j) {
                float acc = upk(b1p, j)
                          + upk(w1p, 3 * j + 0) * l
                          + upk(w1p, 3 * j + 1) * dl
                          + upk(w1p, 3 * j + 2) * a;
                hv[j] = lrelu(acc);
            }
            h1[p].d[0] = pk2(hv[0], hv[1]); h1[p].d[1] = pk2(hv[2], hv[3]);
            h1[p].d[2] = pk2(hv[4], hv[5]); h1[p].d[3] = pk2(hv[6], hv[7]);
        }

        // ---- layer 2 (MFMA), both streams ----
        f32x4 c0, c1;
        c0[0] = up_lo(b2p[0]); c0[1] = up_hi(b2p[0]); c0[2] = up_lo(b2p[1]); c0[3] = up_hi(b2p[1]);
        c1[0] = up_lo(b2p[2]); c1[1] = up_hi(b2p[2]); c1[2] = up_lo(b2p[3]); c1[3] = up_hi(b2p[3]);
        f32x4 acc0[2], acc1[2];
        #pragma unroll
        for (int p = 0; p < 2; ++p) {
            acc0[p] = __builtin_amdgcn_mfma_f32_16x16x32_bf16(w2f[0].b, h1[p].b, c0, 0, 0, 0);
            acc1[p] = __builtin_amdgcn_mfma_f32_16x16x32_bf16(w2f[1].b, h1[p].b, c1, 0, 0, 0);
        }

        // ---- transpose via LDS (one round trip, both streams) ----
        #pragma unroll
        for (int p = 0; p < 2; ++p) {
            unsigned short* X = p ? X1 : X0;
            uint2 st0, st1;
            st0.x = pk2(lrelu(acc0[p][0]), lrelu(acc0[p][1]));
            st0.y = pk2(lrelu(acc0[p][2]), lrelu(acc0[p][3]));
            st1.x = pk2(lrelu(acc1[p][0]), lrelu(acc1[p][1]));
            st1.y = pk2(lrelu(acc1[p][2]), lrelu(acc1[p][3]));
            *(uint2*)&X[n16 * 40 + quad * 4]      = st0;   // rows o=quad*4+r
            *(uint2*)&X[n16 * 40 + 16 + quad * 4] = st1;   // rows o=16+quad*4+r
        }

        FragU hf[2];
        #pragma unroll
        for (int p = 0; p < 2; ++p)
            hf[p].u = *(const us8*)&((p ? X1 : X0)[n16 * 40 + quad * 8]);

        // ---- layer 3 (MFMA), both streams ----
        c0[0] = up_lo(b3p[0]); c0[1] = up_hi(b3p[0]); c0[2] = up_lo(b3p[1]); c0[3] = up_hi(b3p[1]);
        c1[0] = up_lo(b3p[2]); c1[1] = up_hi(b3p[2]); c1[2] = up_lo(b3p[3]); c1[3] = up_hi(b3p[3]);
        #pragma unroll
        for (int p = 0; p < 2; ++p) {
            acc0[p] = __builtin_amdgcn_mfma_f32_16x16x32_bf16(w3f[0].b, hf[p].b, c0, 0, 0, 0);
            acc1[p] = __builtin_amdgcn_mfma_f32_16x16x32_bf16(w3f[1].b, hf[p].b, c1, 0, 0, 0);
        }

        // ---- layer-4 per-quad dot partials + BF components to LDS ----
        #pragma unroll
        for (int p = 0; p < 2; ++p) {
            float d = lrelu(acc0[p][0]) * up_lo(w4p[0]) + lrelu(acc0[p][1]) * up_hi(w4p[0])
                    + lrelu(acc0[p][2]) * up_lo(w4p[1]) + lrelu(acc0[p][3]) * up_hi(w4p[1])
                    + lrelu(acc1[p][0]) * up_lo(w4p[2]) + lrelu(acc1[p][1]) * up_hi(w4p[2])
                    + lrelu(acc1[p][2]) * up_lo(w4p[3]) + lrelu(acc1[p][3]) * up_hi(w4p[3]);

            const int row = (s + p) * 16 + n16;
            comb[w][quad][row] = d;
            const float kk = k0 + k1 * av[p];
            float auxv = kk * ms * ms;                                        // quad 1: kterm
            if (quad == 2) auxv = kk * (l0 + l1 * av[p] - fabsf(lv[p])) * ms; // bflin
            if (quad == 3) auxv = k1 * l1 * av[p] * av[p] * ms;               // coeff
            if (quad >= 1) comb[w][3 + quad][row] = auxv;
        }
    }

    // ---- phase 1: per-(m,row) tanh + quad reduction. Wave w reads only what
    // it wrote itself (same-wave in-order DS) -> no barrier needed here.
    #pragma unroll
    for (int rr = 0; rr < 2; ++rr) {
        const int r = lane + rr * 64;
        const float dot = comb[w][0][r] + comb[w][1][r] + comb[w][2][r] + comb[w][3][r];
        const float bflin = comb[w][5][r];
        const float coeff = comb[w][6][r];
        const float e2x = __expf(2.0f * (dot + b4m));
        const float nn = (1.0f - 2.0f / (e2x + 1.0f)) * NN_RATIO_C;
        red2bf[w][r] = bflin + coeff * nn;
    }

    __syncthreads();

    if (tid < 128) {
        float Ksum = 0.0f, BFsum = 0.0f;
        #pragma unroll
        for (int mm = 0; mm < 8; ++mm) {
            Ksum  += comb[mm][4][tid];     // kterm
            BFsum += red2bf[mm][tid];
        }

        const int b = rowbase + tid;
        const float2 ssv = *(const float2*)&SS[2 * b];
        const float s0 = ssv.x, s1 = ssv.y;
        const float I  = Ivec[0];
        const float bv = Bv[0];
        const float kv = Kv[0];
        const float inv_I = 1.0f / I;

        const float A10 = -(Ksum + kv) * inv_I;
        const float D   = 2.0f * sqrtf(Ksum * I);
        const float A11 = -(D + bv) * inv_I;
        const float B10 = BFsum * inv_I;

        // Reduced 3x3 expm (verified R1-R5)
        const float m01 = DT_C;
        const float m10 = A10 * DT_C, m11 = A11 * DT_C, m12 = B10 * DT_C;

        float p00 = 0.0f, p01 = m01, p02 = 0.0f;
        float p10 = m10,  p11 = m11, p12 = m12;
        float t00 = p00, t01 = p01, t02 = p02;
        float t10 = p10, t11 = p11, t12 = p12;
        #pragma unroll
        for (int k = 2; k <= 16; ++k) {
            float inv = 1.0f / (float)k;
            float q00 = (p01 * m10) * inv;
            float q01 = (p00 * m01 + p01 * m11) * inv;
            float q02 = (p01 * m12) * inv;
            float q10 = (p11 * m10) * inv;
            float q11 = (p10 * m01 + p11 * m11) * inv;
            float q12 = (p11 * m12) * inv;
            p00 = q00; p01 = q01; p02 = q02;
            p10 = q10; p11 = q11; p12 = q12;
            t00 += p00; t01 += p01; t02 += p02;
            t10 += p10; t11 += p11; t12 += p12;
        }
        const float E00 = 1.0f + t00, E01 = t01, c0 = t02;
        const float E10 = t10,        E11 = 1.0f + t11, c1 = t12;

        const float o0 = E00 * s0 + E01 * s1 + c0;
        const float o1 = E10 * s0 + E11 * s1 + c1;

        out[b] = o0;                               // output 0: SSout[:,0:1]
        float2 o12; o12.x = o0; o12.y = o1;        // output 1: SSout[:,:,0]
        *(float2*)&out[BATCH + 2 * b] = o12;
    }
}

extern "C" void kernel_launch(void* const* d_in, const int* in_sizes, int n_in,
                              void* d_out, int out_size, void* d_ws, size_t ws_size,
                              hipStream_t stream) {
    const float* SS     = (const float*)d_in[0];
    const float* Alphas = (const float*)d_in[1];
    const float* K0s    = (const float*)d_in[2];
    const float* K1s    = (const float*)d_in[3];
    const float* L0s    = (const float*)d_in[4];
    const float* L1s    = (const float*)d_in[5];
    const float* Ms     = (const float*)d_in[6];
    const float* I      = (const float*)d_in[7];
    const float* Bv     = (const float*)d_in[8];
    const float* Kv     = (const float*)d_in[9];
    const float* W1     = (const float*)d_in[10];
    const float* b1     = (const float*)d_in[11];
    const float* W2     = (const float*)d_in[12];
    const float* b2     = (const float*)d_in[13];
    const float* W3     = (const float*)d_in[14];
    const float* b3     = (const float*)d_in[15];
    const float* W4     = (const float*)d_in[16];
    const float* b4     = (const float*)d_in[17];
    float* out = (float*)d_out;

    joint_kernel<<<BATCH / 128, 512, 0, stream>>>(
        SS, Alphas, K0s, K1s, L0s, L1s, Ms, I, Bv, Kv,
        W1, b1, W2, b2, W3, b3, W4, b4, out);
}

// Round 7
// 104.212 us; speedup vs baseline: 1.2795x; 1.0011x over previous
//
#include <hip/hip_runtime.h>
#include <math.h>

#define BATCH 65536
#define DT_C 0.0166667f
#define NN_RATIO_C 0.3f

typedef __bf16 bf16x8 __attribute__((ext_vector_type(8)));
typedef __bf16 bf16x2 __attribute__((ext_vector_type(2)));
typedef unsigned short us8 __attribute__((ext_vector_type(8)));
typedef float f32x4 __attribute__((ext_vector_type(4)));

union FragU { us8 u; bf16x8 b; unsigned d[4]; };
union PairU { unsigned u; bf16x2 v; };

__device__ __forceinline__ unsigned short f2bf(float f) {
    union { __bf16 h; unsigned short u; } v;
    v.h = (__bf16)f;                        // hardware RTNE cvt
    return v.u;
}
__device__ __forceinline__ unsigned pk2(float lo, float hi) {
    return (unsigned)f2bf(lo) | ((unsigned)f2bf(hi) << 16);
}
__device__ __forceinline__ float up_lo(unsigned u) { return __uint_as_float(u << 16); }
__device__ __forceinline__ float up_hi(unsigned u) { return __uint_as_float(u & 0xFFFF0000u); }
__device__ __forceinline__ float lrelu(float x) { return fmaxf(x, 0.01f * x); }

// 2-way bf16 dot with f32 accumulate: v_dot2_f32_bf16 if available (gfx940+),
// unpack fallback otherwise (compile-safe either way).
__device__ __forceinline__ float dot2bf(unsigned pa, unsigned pb, float c) {
#if __has_builtin(__builtin_amdgcn_fdot2_f32_bf16)
    PairU ua, ub; ua.u = pa; ub.u = pb;
    return __builtin_amdgcn_fdot2_f32_bf16(ua.v, ub.v, c, false);
#else
    return up_lo(pa) * up_lo(pb) + (up_hi(pa) * up_hi(pb) + c);
#endif
}

// Block = 512 threads = 8 waves; wave w == muscle w; 128 rows/block, 512 blocks.
// __launch_bounds__(512,4): 128-VGPR cap (spill-free; R5 showed cap-85 spills).
// R7 changes vs R6 (R6 ran ~25us, ~5x above the ~5us VALU-issue floor ->
// latency + VALU-volume bound):
//  - explicit 1-iteration-ahead prefetch of SS/Alphas carried across the loop
//    backedge (hides the ~300-600cyc L2 latency that headed each iteration).
//  - layer 1 via v_dot2_f32_bf16: weights pre-packed as (c0,c1)/(c2,bias),
//    inputs packed (l,dl)/(a,1.0) -> 2 dot2 + lrelu per output, zero unpacks
//    (was ~32 unpack ops per stream-iteration).
//  - w4 / bias2 / bias3 kept as hoisted f32 (no per-iteration unpacks).
// Kept (verified R3-R6): MFMA D[o][b]=sum_i W[o][i]*X[b][i] orientation,
// Xbuf stride-40 transpose (<=2-way conflicts), comb slot stride 136
// (136%32==8 -> <=2-way), deferred tanh, single __syncthreads, 3x3 expm.
__global__ __launch_bounds__(512, 4) void joint_kernel(
    const float* __restrict__ SS, const float* __restrict__ Alphas,
    const float* __restrict__ K0s, const float* __restrict__ K1s,
    const float* __restrict__ L0s, const float* __restrict__ L1s,
    const float* __restrict__ Ms, const float* __restrict__ Ivec,
    const float* __restrict__ Bv, const float* __restrict__ Kv,
    const float* __restrict__ W1, const float* __restrict__ b1,
    const float* __restrict__ W2, const float* __restrict__ b2,
    const float* __restrict__ W3, const float* __restrict__ b3,
    const float* __restrict__ W4, const float* __restrict__ b4,
    float* __restrict__ out)
{
    __shared__ unsigned short Xbuf[16][640];  // [wave*2+stream][16 rows * 40]
    __shared__ float comb[8][7][136];         // slots 0-3 dot partials, 4 kterm, 5 bflin, 6 coeff
    __shared__ float red2bf[8][128];

    const int tid  = threadIdx.x;
    const int lane = tid & 63;
    const int w    = tid >> 6;
    const int m    = __builtin_amdgcn_readfirstlane(w);
    const int n16  = lane & 15;
    const int quad = lane >> 4;

    // wave-uniform scalars -> SGPRs
    const float ms = Ms[m];
    const float k0 = K0s[m], k1 = K1s[m], l0 = L0s[m], l1 = L1s[m];
    const float b4m = b4[m];

    // ---- layer-1 weights as dot2 pairs: (c0,c1) and (c2, bias) per output ----
    unsigned w1A[8], w1B[8];
    {
        const float* p1  = W1 + m * 96 + quad * 24;   // W1[m][o=quad*8+j][c]
        const float* pb1 = b1 + m * 32 + quad * 8;
        #pragma unroll
        for (int j = 0; j < 8; ++j) {
            w1A[j] = pk2(p1[3 * j],     p1[3 * j + 1]);
            w1B[j] = pk2(p1[3 * j + 2], pb1[j]);
        }
    }

    // ---- W2/W3 A-fragments (packed bf16), biases & w4 as hoisted f32 ----
    FragU w2f[2], w3f[2];
    #pragma unroll
    for (int t = 0; t < 2; ++t) {
        const int o = t * 16 + n16;
        const float* p2 = W2 + m * 1024 + o * 32 + quad * 8;
        const float* p3 = W3 + m * 1024 + o * 32 + quad * 8;
        f32x4 a2 = *(const f32x4*)p2, c2 = *(const f32x4*)(p2 + 4);
        f32x4 a3 = *(const f32x4*)p3, c3 = *(const f32x4*)(p3 + 4);
        w2f[t].d[0] = pk2(a2[0], a2[1]); w2f[t].d[1] = pk2(a2[2], a2[3]);
        w2f[t].d[2] = pk2(c2[0], c2[1]); w2f[t].d[3] = pk2(c2[2], c2[3]);
        w3f[t].d[0] = pk2(a3[0], a3[1]); w3f[t].d[1] = pk2(a3[2], a3[3]);
        w3f[t].d[2] = pk2(c3[0], c3[1]); w3f[t].d[3] = pk2(c3[2], c3[3]);
    }
    const f32x4 c2lo = *(const f32x4*)(b2 + m * 32 + quad * 4);
    const f32x4 c2hi = *(const f32x4*)(b2 + m * 32 + 16 + quad * 4);
    const f32x4 c3lo = *(const f32x4*)(b3 + m * 32 + quad * 4);
    const f32x4 c3hi = *(const f32x4*)(b3 + m * 32 + 16 + quad * 4);
    const f32x4 w4lo = *(const f32x4*)(W4 + m * 32 + quad * 4);
    const f32x4 w4hi = *(const f32x4*)(W4 + m * 32 + 16 + quad * 4);

    unsigned short* const X0 = &Xbuf[2 * w][0];
    unsigned short* const X1 = &Xbuf[2 * w + 1][0];
    const int rowbase = blockIdx.x * 128;

    // ---- input software pipeline: prefetch iteration s+2's SS/Alphas ----
    float2 ssP[2]; float aP[2];
    #pragma unroll
    for (int p = 0; p < 2; ++p) {
        const int bb = rowbase + p * 16 + n16;
        ssP[p] = *(const float2*)&SS[2 * bb];
        aP[p]  = Alphas[8 * bb + m];
    }

    #pragma unroll 1
    for (int s = 0; s < 8; s += 2) {
        float2 ssC[2]; float aC[2];
        ssC[0] = ssP[0]; ssC[1] = ssP[1];
        aC[0]  = aP[0];  aC[1]  = aP[1];

        // issue next iteration's loads now; consumed after the backedge
        const int sn = (s < 6) ? s + 2 : 0;
        #pragma unroll
        for (int p = 0; p < 2; ++p) {
            const int bb = rowbase + (sn + p) * 16 + n16;
            ssP[p] = *(const float2*)&SS[2 * bb];
            aP[p]  = Alphas[8 * bb + m];
        }

        float lv[2], av[2];
        FragU h1[2];
        #pragma unroll
        for (int p = 0; p < 2; ++p) {
            float a = fminf(fmaxf(aC[p], 0.0f), 1.0f);
            av[p] = a;
            const float l  = ssC[p].x * ms;
            const float dl = ssC[p].y * ms;
            lv[p] = l;

            // layer 1: 2 dot2 + lrelu per output, directly in B-frag layout
            const unsigned ldl = pk2(l, dl);
            const unsigned a1p = pk2(a, 1.0f);
            float hv[8];
            #pragma unroll
            for (int j = 0; j < 8; ++j)
                hv[j] = lrelu(dot2bf(w1A[j], ldl, dot2bf(w1B[j], a1p, 0.0f)));
            h1[p].d[0] = pk2(hv[0], hv[1]); h1[p].d[1] = pk2(hv[2], hv[3]);
            h1[p].d[2] = pk2(hv[4], hv[5]); h1[p].d[3] = pk2(hv[6], hv[7]);
        }

        // ---- layer 2 (MFMA), both streams ----
        f32x4 acc0[2], acc1[2];
        #pragma unroll
        for (int p = 0; p < 2; ++p) {
            acc0[p] = __builtin_amdgcn_mfma_f32_16x16x32_bf16(w2f[0].b, h1[p].b, c2lo, 0, 0, 0);
            acc1[p] = __builtin_amdgcn_mfma_f32_16x16x32_bf16(w2f[1].b, h1[p].b, c2hi, 0, 0, 0);
        }

        // ---- transpose via LDS (one round trip, both streams) ----
        #pragma unroll
        for (int p = 0; p < 2; ++p) {
            unsigned short* X = p ? X1 : X0;
            uint2 st0, st1;
            st0.x = pk2(lrelu(acc0[p][0]), lrelu(acc0[p][1]));
            st0.y = pk2(lrelu(acc0[p][2]), lrelu(acc0[p][3]));
            st1.x = pk2(lrelu(acc1[p][0]), lrelu(acc1[p][1]));
            st1.y = pk2(lrelu(acc1[p][2]), lrelu(acc1[p][3]));
            *(uint2*)&X[n16 * 40 + quad * 4]      = st0;   // rows o=quad*4+r
            *(uint2*)&X[n16 * 40 + 16 + quad * 4] = st1;   // rows o=16+quad*4+r
        }

        FragU hf[2];
        #pragma unroll
        for (int p = 0; p < 2; ++p)
            hf[p].u = *(const us8*)&((p ? X1 : X0)[n16 * 40 + quad * 8]);

        // ---- layer 3 (MFMA), both streams ----
        #pragma unroll
        for (int p = 0; p < 2; ++p) {
            acc0[p] = __builtin_amdgcn_mfma_f32_16x16x32_bf16(w3f[0].b, hf[p].b, c3lo, 0, 0, 0);
            acc1[p] = __builtin_amdgcn_mfma_f32_16x16x32_bf16(w3f[1].b, hf[p].b, c3hi, 0, 0, 0);
        }

        // ---- layer-4 per-quad dot partials + BF components to LDS ----
        #pragma unroll
        for (int p = 0; p < 2; ++p) {
            float d = lrelu(acc0[p][0]) * w4lo[0] + lrelu(acc0[p][1]) * w4lo[1]
                    + lrelu(acc0[p][2]) * w4lo[2] + lrelu(acc0[p][3]) * w4lo[3]
                    + lrelu(acc1[p][0]) * w4hi[0] + lrelu(acc1[p][1]) * w4hi[1]
                    + lrelu(acc1[p][2]) * w4hi[2] + lrelu(acc1[p][3]) * w4hi[3];

            const int row = (s + p) * 16 + n16;
            comb[w][quad][row] = d;
            const float kk = k0 + k1 * av[p];
            float auxv = kk * ms * ms;                                        // quad 1: kterm
            if (quad == 2) auxv = kk * (l0 + l1 * av[p] - fabsf(lv[p])) * ms; // bflin
            if (quad == 3) auxv = k1 * l1 * av[p] * av[p] * ms;               // coeff
            if (quad >= 1) comb[w][3 + quad][row] = auxv;
        }
    }

    // ---- per-(m,row) tanh + quad reduction. Wave w reads only what it wrote
    // itself (same-wave in-order DS) -> no barrier needed here.
    #pragma unroll
    for (int rr = 0; rr < 2; ++rr) {
        const int r = lane + rr * 64;
        const float dot = comb[w][0][r] + comb[w][1][r] + comb[w][2][r] + comb[w][3][r];
        const float bflin = comb[w][5][r];
        const float coeff = comb[w][6][r];
        const float e2x = __expf(2.0f * (dot + b4m));
        const float nn = (1.0f - 2.0f / (e2x + 1.0f)) * NN_RATIO_C;
        red2bf[w][r] = bflin + coeff * nn;
    }

    __syncthreads();

    if (tid < 128) {
        float Ksum = 0.0f, BFsum = 0.0f;
        #pragma unroll
        for (int mm = 0; mm < 8; ++mm) {
            Ksum  += comb[mm][4][tid];     // kterm
            BFsum += red2bf[mm][tid];
        }

        const int b = rowbase + tid;
        const float2 ssv = *(const float2*)&SS[2 * b];
        const float s0 = ssv.x, s1 = ssv.y;
        const float I  = Ivec[0];
        const float bv = Bv[0];
        const float kv = Kv[0];
        const float inv_I = 1.0f / I;

        const float A10 = -(Ksum + kv) * inv_I;
        const float D   = 2.0f * sqrtf(Ksum * I);
        const float A11 = -(D + bv) * inv_I;
        const float B10 = BFsum * inv_I;

        // Reduced 3x3 expm (verified R1-R6)
        const float m01 = DT_C;
        const float m10 = A10 * DT_C, m11 = A11 * DT_C, m12 = B10 * DT_C;

        float p00 = 0.0f, p01 = m01, p02 = 0.0f;
        float p10 = m10,  p11 = m11, p12 = m12;
        float t00 = p00, t01 = p01, t02 = p02;
        float t10 = p10, t11 = p11, t12 = p12;
        #pragma unroll
        for (int k = 2; k <= 16; ++k) {
            float inv = 1.0f / (float)k;
            float q00 = (p01 * m10) * inv;
            float q01 = (p00 * m01 + p01 * m11) * inv;
            float q02 = (p01 * m12) * inv;
            float q10 = (p11 * m10) * inv;
            float q11 = (p10 * m01 + p11 * m11) * inv;
            float q12 = (p11 * m12) * inv;
            p00 = q00; p01 = q01; p02 = q02;
            p10 = q10; p11 = q11; p12 = q12;
            t00 += p00; t01 += p01; t02 += p02;
            t10 += p10; t11 += p11; t12 += p12;
        }
        const float E00 = 1.0f + t00, E01 = t01, c0 = t02;
        const float E10 = t10,        E11 = 1.0f + t11, c1 = t12;

        const float o0 = E00 * s0 + E01 * s1 + c0;
        const float o1 = E10 * s0 + E11 * s1 + c1;

        out[b] = o0;                               // output 0: SSout[:,0:1]
        float2 o12; o12.x = o0; o12.y = o1;        // output 1: SSout[:,:,0]
        *(float2*)&out[BATCH + 2 * b] = o12;
    }
}

extern "C" void kernel_launch(void* const* d_in, const int* in_sizes, int n_in,
                              void* d_out, int out_size, void* d_ws, size_t ws_size,
                              hipStream_t stream) {
    const float* SS     = (const float*)d_in[0];
    const float* Alphas = (const float*)d_in[1];
    const float* K0s    = (const float*)d_in[2];
    const float* K1s    = (const float*)d_in[3];
    const float* L0s    = (const float*)d_in[4];
    const float* L1s    = (const float*)d_in[5];
    const float* Ms     = (const float*)d_in[6];
    const float* I      = (const float*)d_in[7];
    const float* Bv     = (const float*)d_in[8];
    const float* Kv     = (const float*)d_in[9];
    const float* W1     = (const float*)d_in[10];
    const float* b1     = (const float*)d_in[11];
    const float* W2     = (const float*)d_in[12];
    const float* b2     = (const float*)d_in[13];
    const float* W3     = (const float*)d_in[14];
    const float* b3     = (const float*)d_in[15];
    const float* W4     = (const float*)d_in[16];
    const float* b4     = (const float*)d_in[17];
    float* out = (float*)d_out;

    joint_kernel<<<BATCH / 128, 512, 0, stream>>>(
        SS, Alphas, K0s, K1s, L0s, L1s, Ms, I, Bv, Kv,
        W1, b1, W2, b2, W3, b3, W4, b4, out);
}